// Round 3
// baseline (626.930 us; speedup 1.0000x reference)
//
#include <hip/hip_runtime.h>

// ---------------------------------------------------------------------------
// WindowAttention: x[2048,49,512] fp32 -> out[2048,49,512] fp32
// R1: T2 LDS XOR-swizzle + T1 XCD swizzle (bank conflicts -> 0).
// R2: GEMMs ported to the 256x256 8-phase schedule (T3+T4 counted vmcnt(6),
//     T5 setprio, raw s_barrier, double-buffered 128KiB LDS, 8 waves).
// ---------------------------------------------------------------------------

typedef unsigned short ushort_t;
typedef __bf16 bf16x8 __attribute__((ext_vector_type(8)));
typedef float f32x4 __attribute__((ext_vector_type(4)));
typedef unsigned short us8 __attribute__((ext_vector_type(8)));

#define SCALE_F 0.17677669529663687f   // 32^-0.5
constexpr size_t QKV_REG = 2048ULL * 16 * 49 * 32;   // elems per q/k/v region

// RNE float -> bf16 (as raw ushort)
__device__ __forceinline__ ushort_t f2bf(float f) {
  unsigned u = __builtin_bit_cast(unsigned, f);
  u += 0x7FFFu + ((u >> 16) & 1u);
  return (ushort_t)(u >> 16);
}

// async global->LDS, 16B per lane; lds base must be wave-uniform
__device__ __forceinline__ void gload_lds16(const void* g, void* l) {
  __builtin_amdgcn_global_load_lds(
      (const __attribute__((address_space(1))) void*)g,
      (__attribute__((address_space(3))) void*)l, 16, 0, 0);
}

// ---------------------------------------------------------------------------
// fp32 -> bf16 conversion, 4 elems/thread
// ---------------------------------------------------------------------------
__global__ __launch_bounds__(256) void k_cvt(const float* __restrict__ in,
                                             ushort_t* __restrict__ out, int n4) {
  int i = blockIdx.x * blockDim.x + threadIdx.x;
  if (i >= n4) return;
  float4 v = reinterpret_cast<const float4*>(in)[i];
  ushort4 o = make_ushort4(f2bf(v.x), f2bf(v.y), f2bf(v.z), f2bf(v.w));
  reinterpret_cast<ushort4*>(out)[i] = o;
}

// ---------------------------------------------------------------------------
// 8-phase 256x256 GEMM: C[m][o] = sum_k A[m][k]*W[o][k] + bias[o], K=512.
// 8 waves (2M x 4N), per-wave 128x64 output = 8x4 frags of 16x16x32 bf16.
// LDS: 2 K-tile buffers x (A 256x64 + W 256x64) bf16 = 128 KiB, chunk-XOR
// swizzled (slot(row,c) holds logical chunk c ^ (row&7); staged via
// pre-swizzled global source since global_load_lds writes linearly).
// Per K-tile: 4 phases {ds_reads, stage half-tile(s), barrier, MFMA x16,
// barrier}; vmcnt(6) once per tile at phase-4 end (3 half-tiles in flight).
// Stage slots: ph1 -> A1(t+1) [other buf, tile t-1 retired];
//   ph3 -> B0(t+2) [B0 free after ph2]; ph4 -> A0(t+2) [A free after ph3],
//   B1(t+2) [free after ph2]. vmcnt(6) at ph4 retires all of tile t+1.
// EPI=0: scatter to qkv layout [3][B,H,N,d] bf16.  EPI=1: fp32 out.
// ---------------------------------------------------------------------------
template <int EPI>
__global__ __launch_bounds__(512, 2) void k_gemm8(const ushort_t* __restrict__ A,
                                                  const ushort_t* __restrict__ W,
                                                  const float* __restrict__ bias,
                                                  ushort_t* __restrict__ out_qkv,
                                                  float* __restrict__ out_f,
                                                  int nt_o) {
  __shared__ __align__(16) ushort_t As[2][256][64];
  __shared__ __align__(16) ushort_t Ws[2][256][64];

  const int tid  = threadIdx.x;
  const int lane = tid & 63;
  const int wv   = tid >> 6;          // wave id 0..7
  const int wm   = wv >> 2, wn = wv & 3;

  // bijective XCD swizzle (gridDim.x % 8 == 0)
  const int cpx = gridDim.x >> 3;
  const int lid = (blockIdx.x & 7) * cpx + (blockIdx.x >> 3);
  const int bm  = lid / nt_o;
  const int bo  = lid - bm * nt_o;
  const size_t m0 = (size_t)bm * 256;
  const int o0    = bo * 256;

  // staging: wave wv covers segments {wv*2, wv*2+1} of each 128x64 half-tile.
  // lane l -> row seg*8 + (l>>3), slot chunk l&7; logical chunk = (l&7)^(l>>3)
  const int seg0 = wv * 2;
  const int srow = seg0 * 8 + (lane >> 3);
  const int scol = ((lane & 7) ^ (lane >> 3)) * 8;
  const ushort_t* Ag = A + (m0 + srow) * 512 + scol;
  const ushort_t* Wg = W + (size_t)(o0 + srow) * 512 + scol;

  auto stageA = [&](int bb, int h, int kt) {
    const ushort_t* g = Ag + (size_t)h * (128 * 512) + kt * 64;
    gload_lds16(g,           &As[bb][h * 128 + seg0 * 8][0]);
    gload_lds16(g + 8 * 512, &As[bb][h * 128 + seg0 * 8 + 8][0]);
  };
  auto stageW = [&](int bb, int h, int kt) {
    const ushort_t* g = Wg + (size_t)h * (128 * 512) + kt * 64;
    gload_lds16(g,           &Ws[bb][h * 128 + seg0 * 8][0]);
    gload_lds16(g + 8 * 512, &Ws[bb][h * 128 + seg0 * 8 + 8][0]);
  };

  const int fr  = lane & 15;
  const int cb0 = lane >> 4;
  auto readA = [&](int bb, int mi, int kk) -> uint4 {
    const int row = wm * 128 + mi * 16 + fr;
    const int ch  = (kk * 4 + cb0) ^ (fr & 7);
    return *reinterpret_cast<const uint4*>(&As[bb][row][ch * 8]);
  };
  auto readW = [&](int bb, int ni, int kk) -> uint4 {
    const int row = wn * 64 + ni * 16 + fr;
    const int ch  = (kk * 4 + cb0) ^ (fr & 7);
    return *reinterpret_cast<const uint4*>(&Ws[bb][row][ch * 8]);
  };
  auto MF = [&](uint4 a, uint4 b, f32x4 c) -> f32x4 {
    return __builtin_amdgcn_mfma_f32_16x16x32_bf16(
        __builtin_bit_cast(bf16x8, a), __builtin_bit_cast(bf16x8, b), c, 0, 0, 0);
  };

  f32x4 acc[8][4];
#pragma unroll
  for (int i = 0; i < 8; i++)
#pragma unroll
    for (int j = 0; j < 4; j++) acc[i][j] = f32x4{0.f, 0.f, 0.f, 0.f};

  uint4 am[4][2], bn[4][2];

  // prologue: tile0 full + tile1 {B0,B1,A0} = 14 loads; vmcnt(6) -> tile0 done
  stageA(0, 0, 0); stageA(0, 1, 0); stageW(0, 0, 0); stageW(0, 1, 0);
  stageW(1, 0, 1); stageW(1, 1, 1); stageA(1, 0, 1);
  asm volatile("s_waitcnt vmcnt(6)" ::: "memory");
  __builtin_amdgcn_s_barrier();

  for (int t = 0; t < 8; t += 2) {
#pragma unroll
    for (int hf = 0; hf < 2; ++hf) {
      const int bb  = hf;
      const int tt  = t + hf;
      const int kt1 = (tt + 1 < 8) ? (tt + 1) : 7;   // clamped (redundant ok)
      const int kt2 = (tt + 2 < 8) ? (tt + 2) : 7;

      // ---- phase 1: read A m0-half + B n0-half; stage A1(t+1) ----
#pragma unroll
      for (int j = 0; j < 4; ++j)
#pragma unroll
        for (int kk = 0; kk < 2; ++kk) am[j][kk] = readA(bb, j, kk);
#pragma unroll
      for (int ni = 0; ni < 2; ++ni)
#pragma unroll
        for (int kk = 0; kk < 2; ++kk) bn[ni][kk] = readW(bb, ni, kk);
      stageA(bb ^ 1, 1, kt1);
      __builtin_amdgcn_s_barrier();
      __builtin_amdgcn_s_setprio(1);
#pragma unroll
      for (int j = 0; j < 4; ++j)
#pragma unroll
        for (int ni = 0; ni < 2; ++ni)
#pragma unroll
          for (int kk = 0; kk < 2; ++kk)
            acc[j][ni] = MF(am[j][kk], bn[ni][kk], acc[j][ni]);
      __builtin_amdgcn_s_setprio(0);
      __builtin_amdgcn_s_barrier();

      // ---- phase 2: read B n1-half ----
#pragma unroll
      for (int ni = 2; ni < 4; ++ni)
#pragma unroll
        for (int kk = 0; kk < 2; ++kk) bn[ni][kk] = readW(bb, ni, kk);
      __builtin_amdgcn_s_barrier();
      __builtin_amdgcn_s_setprio(1);
#pragma unroll
      for (int j = 0; j < 4; ++j)
#pragma unroll
        for (int ni = 2; ni < 4; ++ni)
#pragma unroll
          for (int kk = 0; kk < 2; ++kk)
            acc[j][ni] = MF(am[j][kk], bn[ni][kk], acc[j][ni]);
      __builtin_amdgcn_s_setprio(0);
      __builtin_amdgcn_s_barrier();

      // ---- phase 3: read A m1-half; stage B0(t+2) ----
#pragma unroll
      for (int j = 0; j < 4; ++j)
#pragma unroll
        for (int kk = 0; kk < 2; ++kk) am[j][kk] = readA(bb, 4 + j, kk);
      stageW(bb, 0, kt2);
      __builtin_amdgcn_s_barrier();
      __builtin_amdgcn_s_setprio(1);
#pragma unroll
      for (int j = 0; j < 4; ++j)
#pragma unroll
        for (int ni = 0; ni < 2; ++ni)
#pragma unroll
          for (int kk = 0; kk < 2; ++kk)
            acc[4 + j][ni] = MF(am[j][kk], bn[ni][kk], acc[4 + j][ni]);
      __builtin_amdgcn_s_setprio(0);
      __builtin_amdgcn_s_barrier();

      // ---- phase 4: stage A0(t+2), B1(t+2); vmcnt(6) gates next tile ----
      stageA(bb, 0, kt2);
      stageW(bb, 1, kt2);
      __builtin_amdgcn_s_barrier();
      __builtin_amdgcn_s_setprio(1);
#pragma unroll
      for (int j = 0; j < 4; ++j)
#pragma unroll
        for (int ni = 2; ni < 4; ++ni)
#pragma unroll
          for (int kk = 0; kk < 2; ++kk)
            acc[4 + j][ni] = MF(am[j][kk], bn[ni][kk], acc[4 + j][ni]);
      __builtin_amdgcn_s_setprio(0);
      asm volatile("s_waitcnt vmcnt(6)" ::: "memory");
      __builtin_amdgcn_s_barrier();
    }
  }
  asm volatile("s_waitcnt vmcnt(0)" ::: "memory");

  // ---- epilogue ----
  const int colbase = lane & 15;
  const int rg      = (lane >> 4) * 4;

  if constexpr (EPI == 1) {
#pragma unroll
    for (int ni = 0; ni < 4; ++ni) {
      const int o = o0 + wn * 64 + ni * 16 + colbase;
      const float bv = bias[o];
#pragma unroll
      for (int mi = 0; mi < 8; ++mi) {
        const size_t mrow = m0 + wm * 128 + mi * 16 + rg;
#pragma unroll
        for (int r = 0; r < 4; ++r)
          out_f[(mrow + r) * 512 + o] = acc[mi][ni][r] + bv;
      }
    }
  } else {
#pragma unroll
    for (int mi = 0; mi < 8; ++mi) {
#pragma unroll
      for (int r = 0; r < 4; ++r) {
        const int tkn = (int)m0 + wm * 128 + mi * 16 + rg + r;  // token
        const int b = tkn / 49;
        const int n = tkn - b * 49;
#pragma unroll
        for (int ni = 0; ni < 4; ++ni) {
          const int o = o0 + wn * 64 + ni * 16 + colbase;
          const int which = o >> 9;
          const int h = (o >> 5) & 15;
          const int dd = o & 31;
          const size_t dst = (size_t)which * QKV_REG +
                             (((size_t)b * 16 + h) * 49 + n) * 32 + dd;
          out_qkv[dst] = f2bf(acc[mi][ni][r] + bias[o]);
        }
      }
    }
  }
}

// ---------------------------------------------------------------------------
// Attention: one block per (b,h). 4 waves, wave mt owns query rows
// [16*mt, 16*mt+16). S = scale*Q K^T + mask ; softmax ; O = P V / rowsum.
// Vt and Ps use the chunk-XOR-swizzled LDS layout.
// ---------------------------------------------------------------------------
__global__ __launch_bounds__(256) void k_attn(const ushort_t* __restrict__ qkv,
                                              const float* __restrict__ mask,
                                              ushort_t* __restrict__ aout) {
  __shared__ __align__(16) ushort_t Vt[32][64];      // V transposed (swizzled)
  __shared__ __align__(16) ushort_t Ps[4][16][64];   // per-wave P tile (swizzled)

  const int tid  = threadIdx.x;
  const int lane = tid & 63;
  const int mt   = tid >> 6;
  const int bh   = blockIdx.x;
  const int b    = bh >> 4, h = bh & 15;
  const int w    = b & 63;
  const size_t base = (size_t)bh * (49 * 32);
  const ushort_t* qb = qkv + base;
  const ushort_t* kb = qkv + QKV_REG + base;
  const ushort_t* vb = qkv + 2 * QKV_REG + base;

  reinterpret_cast<uint4*>(&Vt[0][0])[tid] = make_uint4(0, 0, 0, 0);
  __syncthreads();
  if (tid < 196) {
    const int n = tid >> 2, d0 = (tid & 3) * 8;
    uint4 raw = *reinterpret_cast<const uint4*>(vb + n * 32 + d0);
    us8 e = __builtin_bit_cast(us8, raw);
#pragma unroll
    for (int j = 0; j < 8; j++)
      Vt[d0 + j][(((n >> 3) ^ j) << 3) | (n & 7)] = e[j];
  }
  __syncthreads();

  const int arow = lane & 15;
  const int kc   = (lane >> 4) * 8;

  uint4 qraw = *reinterpret_cast<const uint4*>(qb + (mt * 16 + arow) * 32 + kc);
  bf16x8 qa = __builtin_bit_cast(bf16x8, qraw);
  f32x4 s[4];
#pragma unroll
  for (int ni = 0; ni < 4; ni++) {
    uint4 kraw = *reinterpret_cast<const uint4*>(kb + (ni * 16 + arow) * 32 + kc);
    f32x4 z = {0.f, 0.f, 0.f, 0.f};
    s[ni] = __builtin_amdgcn_mfma_f32_16x16x32_bf16(
        qa, __builtin_bit_cast(bf16x8, kraw), z, 0, 0, 0);
  }

  const int rg = (lane >> 4) * 4;
  float rsum[4];
#pragma unroll
  for (int r = 0; r < 4; r++) {
    const int qr = mt * 16 + rg + r;
    float sv[4];
    float mx = -1e30f;
#pragma unroll
    for (int ni = 0; ni < 4; ni++) {
      const int col = ni * 16 + arow;
      float v;
      if (qr < 49 && col < 49)
        v = s[ni][r] * SCALE_F + mask[(size_t)w * 2401 + qr * 49 + col];
      else
        v = -1e30f;
      sv[ni] = v;
      mx = fmaxf(mx, v);
    }
#pragma unroll
    for (int off = 1; off < 16; off <<= 1) mx = fmaxf(mx, __shfl_xor(mx, off));
    float sum = 0.f;
    const int prow = rg + r;
#pragma unroll
    for (int ni = 0; ni < 4; ni++) {
      float p = __expf(sv[ni] - mx);
      sum += p;
      const int pcol = ni * 16 + arow;
      Ps[mt][prow][(((pcol >> 3) ^ (prow & 7)) << 3) | (pcol & 7)] = f2bf(p);
    }
#pragma unroll
    for (int off = 1; off < 16; off <<= 1) sum += __shfl_xor(sum, off);
    rsum[r] = sum;
  }

  __syncthreads();

  f32x4 o0 = {0.f, 0.f, 0.f, 0.f}, o1 = {0.f, 0.f, 0.f, 0.f};
#pragma unroll
  for (int kk = 0; kk < 2; kk++) {
    const int ch = kk * 4 + (lane >> 4);
    const int cb = ((ch ^ (lane & 7)) << 3);
    uint4 praw = *reinterpret_cast<const uint4*>(&Ps[mt][arow][cb]);
    bf16x8 pa = __builtin_bit_cast(bf16x8, praw);
    uint4 v0 = *reinterpret_cast<const uint4*>(&Vt[arow][cb]);
    uint4 v1 = *reinterpret_cast<const uint4*>(&Vt[16 + arow][cb]);
    o0 = __builtin_amdgcn_mfma_f32_16x16x32_bf16(pa, __builtin_bit_cast(bf16x8, v0), o0, 0, 0, 0);
    o1 = __builtin_amdgcn_mfma_f32_16x16x32_bf16(pa, __builtin_bit_cast(bf16x8, v1), o1, 0, 0, 0);
  }

#pragma unroll
  for (int r = 0; r < 4; r++) {
    const int qr = mt * 16 + rg + r;
    if (qr < 49) {
      const float inv = 1.f / rsum[r];
      aout[((size_t)b * 49 + qr) * 512 + h * 32 + arow]      = f2bf(o0[r] * inv);
      aout[((size_t)b * 49 + qr) * 512 + h * 32 + 16 + arow] = f2bf(o1[r] * inv);
    }
  }
}

// ---------------------------------------------------------------------------
// launch
// ---------------------------------------------------------------------------
extern "C" void kernel_launch(void* const* d_in, const int* in_sizes, int n_in,
                              void* d_out, int out_size, void* d_ws, size_t ws_size,
                              hipStream_t stream) {
  const float* x      = (const float*)d_in[0];
  const float* mask   = (const float*)d_in[1];
  const float* W_qkv  = (const float*)d_in[2];
  const float* b_qkv  = (const float*)d_in[3];
  const float* W_proj = (const float*)d_in[4];
  const float* b_proj = (const float*)d_in[5];
  float* out = (float*)d_out;

  // ws layout (bf16 elems): xb | qkv(q,k,v) | attn_out | Wqkv_b | Wproj_b
  ushort_t* ws     = (ushort_t*)d_ws;
  ushort_t* xb     = ws;                                  // 51,380,224
  ushort_t* qkvb   = ws + 51380224UL;                     // 3*51,380,224
  ushort_t* aoutb  = ws + 205520896UL;                    // 51,380,224
  ushort_t* wqkvb  = ws + 256901120UL;                    // 786,432
  ushort_t* wprojb = ws + 257687552UL;                    // 262,144

  const int n4x = 51380224 / 4, n4q = 786432 / 4, n4p = 262144 / 4;
  k_cvt<<<(n4x + 255) / 256, 256, 0, stream>>>(x, xb, n4x);
  k_cvt<<<(n4q + 255) / 256, 256, 0, stream>>>(W_qkv, wqkvb, n4q);
  k_cvt<<<(n4p + 255) / 256, 256, 0, stream>>>(W_proj, wprojb, n4p);

  // GEMM1: [100352,512] x [1536,512]^T -> qkv scatter. 392 x 6 tiles of 256².
  k_gemm8<0><<<392 * 6, 512, 0, stream>>>(xb, wqkvb, b_qkv, qkvb, nullptr, 6);

  // attention: one block per (b,h)
  k_attn<<<2048 * 16, 256, 0, stream>>>(qkvb, mask, aoutb);

  // GEMM2: [100352,512] x [512,512]^T + bias -> fp32 out. 392 x 2 tiles.
  k_gemm8<1><<<392 * 2, 512, 0, stream>>>(aoutb, wprojb, b_proj, nullptr, out, 2);
}